// Round 20
// baseline (171.404 us; speedup 1.0000x reference)
//
#include <hip/hip_runtime.h>
#include <hip/hip_bf16.h>
#include <stdint.h>

typedef unsigned short u16;
typedef __attribute__((ext_vector_type(8))) short short8;
typedef __attribute__((ext_vector_type(4))) float floatx4;
typedef __attribute__((ext_vector_type(16))) float floatx16;
typedef __attribute__((ext_vector_type(4))) unsigned uint4v;
typedef __attribute__((ext_vector_type(2))) unsigned uint2v;

#define DEV static __device__ __forceinline__

DEV u16 f2bf(float f) {
  __hip_bfloat16 h = __float2bfloat16(f);
  return __builtin_bit_cast(u16, h);
}

DEV float fexp2(float x) {
  float r;
  asm("v_exp_f32 %0, %1" : "=v"(r) : "v"(x));
  return r;
}

DEV unsigned cvtpk(float lo, float hi) {  // packs (lo,hi) -> 2x bf16 in one u32
  unsigned r;
  asm("v_cvt_pk_bf16_f32 %0, %1, %2" : "=v"(r) : "v"(lo), "v"(hi));
  return r;
}

// v_permlane32_swap_b32 via the intrinsic (pure function -> no register-alias UB)
DEV void pswap(unsigned& a, unsigned& b) {
  uint2v r = __builtin_amdgcn_permlane32_swap(a, b, false, false);
  a = r[0];
  b = r[1];
}

// x = (lane<32 ? self : partner), y = (lane<32 ? partner : self); symmetric combines valid.
DEV void cross32(float v, float& x, float& y) {
  unsigned a = __builtin_bit_cast(unsigned, v), b = a;
  pswap(a, b);
  x = __builtin_bit_cast(float, a);
  y = __builtin_bit_cast(float, b);
}

DEV floatx4 mfma16(short8 a, short8 b, floatx4 c) {
  return __builtin_amdgcn_mfma_f32_16x16x32_bf16(a, b, c, 0, 0, 0);
}
DEV floatx16 mfma32(short8 a, short8 b, floatx16 c) {
  return __builtin_amdgcn_mfma_f32_32x32x16_bf16(a, b, c, 0, 0, 0);
}

DEV void gload_lds16(const void* g, void* l) {
  __builtin_amdgcn_global_load_lds(
      (void __attribute__((address_space(1)))*)(g),
      (void __attribute__((address_space(3)))*)(l),
      16, 0, 0);
}

// ---------------------------------------------------------------- fused cast f32->bf16
__global__ void cast3_kernel(const float* __restrict__ x, const float* __restrict__ win,
                             const float* __restrict__ wout,
                             u16* __restrict__ xb, u16* __restrict__ winb,
                             u16* __restrict__ woutb) {
  int i = blockIdx.x * 256 + threadIdx.x;
  const float* src;
  u16* dst;
  int off;
  if (i < 2097152) {
    src = x; dst = xb; off = i;
  } else if (i < 2883584) {
    src = win; dst = winb; off = i - 2097152;
  } else {
    src = wout; dst = woutb; off = i - 2883584;
  }
  float4 v = reinterpret_cast<const float4*>(src)[off];
  ushort4 o;
  o.x = f2bf(v.x); o.y = f2bf(v.y); o.z = f2bf(v.z); o.w = f2bf(v.w);
  reinterpret_cast<ushort4*>(dst)[off] = o;
}

// ---------------------------------------------------------------- GEMM  C[M,N] = A[M,K] * W[N,K]^T
// FUSED single-phase K-tile (A/B test vs round-11's 2-phase): counted vmcnt(6) +
// 3-buffer rotation kept; mid-tile barrier REMOVED (r12 showed adding barriers
// hurt at 1 block/CU -> removing should help). One barrier per K-tile; compiler
// interleaves ds_read/stage/MFMA freely within the fused region.
template <int MODE>
__global__ __launch_bounds__(512, 2)
void gemm_bt(const u16* __restrict__ A, const u16* __restrict__ W,
             int M, int N, int K,
             u16* __restrict__ Qb, u16* __restrict__ Kb, u16* __restrict__ Vb,
             float* __restrict__ C) {
  __shared__ u16 As[3][128 * 64];   // 48 KB
  __shared__ u16 Bs[3][256 * 64];   // 96 KB
  const int tid = threadIdx.x;
  const int wave = tid >> 6, lane = tid & 63;
  const int lr = lane & 15, lg = lane >> 4;
  const int m0 = blockIdx.y * 128, n0 = blockIdx.x * 256;
  const int mq0 = (wave >> 2) * 64, nq0 = (wave & 3) * 64;

  floatx4 acc[4][4];
#pragma unroll
  for (int i = 0; i < 4; ++i)
#pragma unroll
    for (int j = 0; j < 4; ++j) acc[i][j] = (floatx4)0.f;

  const int NT = K >> 6;  // K-tiles of 64

  auto stage_a = [&](int t, int bi) {
#pragma unroll
    for (int i = 0; i < 2; ++i) {
      int s = i * 512 + tid;
      int row = s >> 3;
      int col = ((s & 7) ^ (row & 7)) * 8;
      gload_lds16(&A[(size_t)(m0 + row) * K + t * 64 + col], &As[bi][(size_t)s * 8]);
    }
  };
  auto stage_b = [&](int t, int bi) {
#pragma unroll
    for (int i = 0; i < 4; ++i) {
      int s = i * 512 + tid;
      int row = s >> 3;
      int col = ((s & 7) ^ (row & 7)) * 8;
      gload_lds16(&W[(size_t)(n0 + row) * K + t * 64 + col], &Bs[bi][(size_t)s * 8]);
    }
  };

  // prologue: tiles 0,1 into bufs 0,1 (12 loads outstanding)
  stage_a(0, 0);
  stage_b(0, 0);
  stage_a(1, 1);
  stage_b(1, 1);

  int bi = 0;
  for (int t = 0; t < NT; ++t) {
    // ---- tile top: own tile-t loads landed (t+1's 6 in flight), all waves sync
    if (t < NT - 1) {
      asm volatile("s_waitcnt vmcnt(6)" ::: "memory");
    } else {
      asm volatile("s_waitcnt vmcnt(0)" ::: "memory");
    }
    __builtin_amdgcn_sched_barrier(0);
    __builtin_amdgcn_s_barrier();
    __builtin_amdgcn_sched_barrier(0);

    int b2 = bi + 2; if (b2 >= 3) b2 -= 3;
    const bool do_st = (t + 2 < NT);

    // ---- fused phase: read all frags; stage tile t+2; 32 MFMA
    short8 af[4][2], bf[4][2];
#pragma unroll
    for (int i = 0; i < 4; ++i) {
      int row = mq0 + i * 16 + lr;
#pragma unroll
      for (int kh = 0; kh < 2; ++kh)
        af[i][kh] = *reinterpret_cast<const short8*>(
            &As[bi][row * 64 + (((kh * 4 + lg) ^ (row & 7)) * 8)]);
    }
#pragma unroll
    for (int j = 0; j < 4; ++j) {
      int row = nq0 + j * 16 + lr;
#pragma unroll
      for (int kh = 0; kh < 2; ++kh)
        bf[j][kh] = *reinterpret_cast<const short8*>(
            &Bs[bi][row * 64 + (((kh * 4 + lg) ^ (row & 7)) * 8)]);
    }
    if (do_st) {
      stage_a(t + 2, b2);
      stage_b(t + 2, b2);
    }
    __builtin_amdgcn_s_setprio(1);
#pragma unroll
    for (int kh = 0; kh < 2; ++kh)
#pragma unroll
      for (int i = 0; i < 4; ++i)
#pragma unroll
        for (int j = 0; j < 4; ++j)
          acc[i][j] = mfma16(af[i][kh], bf[j][kh], acc[i][j]);
    __builtin_amdgcn_s_setprio(0);

    if (++bi == 3) bi = 0;
  }

  if (MODE == 0) {
#pragma unroll
    for (int j = 0; j < 4; ++j) {
      int n = n0 + nq0 + j * 16 + lr;
      int which = n >> 10;
      int d = n & 1023;
      int h = d >> 6, dh = d & 63;
      u16* dst = (which == 0) ? Qb : ((which == 1) ? Kb : Vb);
      float scale = (which == 0) ? 0.18033688f : 1.0f;  // 0.125 * log2(e)
#pragma unroll
      for (int i = 0; i < 4; ++i) {
#pragma unroll
        for (int r = 0; r < 4; ++r) {
          int m = m0 + mq0 + i * 16 + lg * 4 + r;
          int b = m >> 11, s = m & 2047;
          dst[((size_t)(b * 16 + h) * 2048 + s) * 64 + dh] = f2bf(acc[i][j][r] * scale);
        }
      }
    }
  } else {
#pragma unroll
    for (int i = 0; i < 4; ++i)
#pragma unroll
      for (int j = 0; j < 4; ++j)
#pragma unroll
        for (int r = 0; r < 4; ++r) {
          int m = m0 + mq0 + i * 16 + lg * 4 + r;
          int n = n0 + nq0 + j * 16 + lr;
          C[(size_t)m * N + n] = acc[i][j][r];
        }
  }
}

// ---------------------------------------------------------------- flash attention (causal)
// ROUND-16 VERSION (measured best, attn 75.2 us): round-11 swapped-operand
// structure + bijective XCD swizzle (K/V L2-resident, FETCH 143->30 MB).
__global__ __launch_bounds__(256, 2)
void attn_kernel(const u16* __restrict__ Qb, const u16* __restrict__ Kb,
                 const u16* __restrict__ Vb, u16* __restrict__ Ob) {
  // bijective remap (lid <-> (xcd, k)): bh = xcd*8 + (k&7), bx = k>>3
  const int lid = (int)blockIdx.x + 8 * (int)blockIdx.y;
  const int xcd = lid & 7;
  const int kk = lid >> 3;          // 0..63
  const int bh = xcd * 8 + (kk & 7);
  const int bx = kk >> 3;           // 0..7, replaces blockIdx.x
  const u16* Qh = Qb + (size_t)bh * 2048 * 64;
  const u16* Kh = Kb + (size_t)bh * 2048 * 64;
  const u16* Vh = Vb + (size_t)bh * 2048 * 64;

  __shared__ u16 smem[3][8192];

  const int tid = threadIdx.x, wave = tid >> 6, lane = tid & 63;
  const int ln31 = lane & 31, hi = lane >> 5;
  const int swz = (lane & 7) * 8;
  const int b = bh >> 4, h = bh & 15;

  const int vp = tid & 31, vc8 = tid >> 5;

  auto stage_k = [&](int kvbase, u16* buf) {
#pragma unroll
    for (int i = 0; i < 2; ++i) {
      int s = i * 256 + tid;
      int row = s >> 3;
      int col = ((s & 7) ^ (row & 7)) * 8;
      gload_lds16(&Kh[(size_t)(kvbase + row) * 64 + col], &buf[(size_t)s * 8]);
    }
  };
  auto load_v = [&](int kvbase, short8& v0, short8& v1) {
    v0 = *reinterpret_cast<const short8*>(&Vh[(size_t)(kvbase + 2 * vp) * 64 + vc8 * 8]);
    v1 = *reinterpret_cast<const short8*>(&Vh[(size_t)(kvbase + 2 * vp + 1) * 64 + vc8 * 8]);
  };
  auto write_v = [&](u16* buf, short8 v0, short8 v1) {
#pragma unroll
    for (int j = 0; j < 8; ++j) {
      int d = vc8 * 8 + j;
      uint32_t pk = (uint32_t)(u16)v0[j] | ((uint32_t)(u16)v1[j] << 16);
      *reinterpret_cast<uint32_t*>(&buf[4096 + d * 64 + ((2 * vp) ^ ((d & 7) * 8))]) = pk;
    }
  };

  for (int ph = 0; ph < 2; ++ph) {
    const int tq = ph ? (15 - bx) : bx;
    const int q0w = tq * 128 + wave * 32;
    const int qrow = q0w + ln31;

    short8 qf[4];
#pragma unroll
    for (int c = 0; c < 4; ++c)
      qf[c] = *reinterpret_cast<const short8*>(
          &Qh[(size_t)qrow * 64 + c * 16 + hi * 8]);

    floatx16 accO0 = (floatx16)0.f, accO1 = (floatx16)0.f;
    float m_run = -1e30f, l_run = 0.f;

    auto do_qk = [&](int kvq, floatx16& SQ0, floatx16& SQ1, const u16* Ksq) {
      if (kvq > q0w + 31) return;
      SQ0 = (floatx16)0.f;
      SQ1 = (floatx16)0.f;
      __builtin_amdgcn_s_setprio(1);
#pragma unroll
      for (int c = 0; c < 4; ++c) {
        short8 kfA = *reinterpret_cast<const short8*>(
            &Ksq[ln31 * 64 + ((c * 16 + hi * 8) ^ swz)]);
        short8 kfB = *reinterpret_cast<const short8*>(
            &Ksq[(32 + ln31) * 64 + ((c * 16 + hi * 8) ^ swz)]);
        SQ0 = mfma32(kfA, qf[c], SQ0);
        SQ1 = mfma32(kfB, qf[c], SQ1);
      }
      __builtin_amdgcn_s_setprio(0);
    };

    auto do_smpv = [&](int kv0_, floatx16& SS0, floatx16& SS1, const u16* bufv) {
      if (kv0_ > q0w + 31) return;
      if (kv0_ + 63 > q0w) {
#pragma unroll
        for (int reg = 0; reg < 16; ++reg) {
          int kvA = kv0_ + (reg & 3) + 8 * (reg >> 2) + 4 * hi;
          if (kvA > qrow) SS0[reg] = -1e30f;
          if (kvA + 32 > qrow) SS1[reg] = -1e30f;
        }
      }
      float m8[8];
#pragma unroll
      for (int i = 0; i < 8; ++i)
        m8[i] = fmaxf(fmaxf(SS0[i], SS0[i + 8]), fmaxf(SS1[i], SS1[i + 8]));
      float mx = fmaxf(fmaxf(fmaxf(m8[0], m8[1]), fmaxf(m8[2], m8[3])),
                       fmaxf(fmaxf(m8[4], m8[5]), fmaxf(m8[6], m8[7])));
      {
        float xa, xb;
        cross32(mx, xa, xb);
        mx = fmaxf(xa, xb);
      }
      bool small_ = (mx <= m_run + 8.f);
      if (!__all(small_)) {
        float mn = fmaxf(m_run, mx);
        float fac = fexp2(m_run - mn);
        m_run = mn;
        l_run *= fac;
        accO0 *= fac;
        accO1 *= fac;
      }
#pragma unroll
      for (int i = 0; i < 16; ++i) SS0[i] = fexp2(SS0[i] - m_run);
#pragma unroll
      for (int i = 0; i < 16; ++i) SS1[i] = fexp2(SS1[i] - m_run);
      float a8[8];
#pragma unroll
      for (int i = 0; i < 8; ++i)
        a8[i] = (SS0[i] + SS0[i + 8]) + (SS1[i] + SS1[i + 8]);
      float rs = ((a8[0] + a8[1]) + (a8[2] + a8[3])) + ((a8[4] + a8[5]) + (a8[6] + a8[7]));
      {
        float xa, xb;
        cross32(rs, xa, xb);
        rs = xa + xb;
      }
      l_run += rs;
      short8 pf[4];
#define BUILD_PF(idx, S, base)                                        \
      {                                                               \
        unsigned u01 = cvtpk(S[base + 0], S[base + 1]);               \
        unsigned u23 = cvtpk(S[base + 2], S[base + 3]);               \
        unsigned u45 = cvtpk(S[base + 4], S[base + 5]);               \
        unsigned u67 = cvtpk(S[base + 6], S[base + 7]);               \
        pswap(u01, u45);                                              \
        pswap(u23, u67);                                              \
        uint4v w; w.x = u01; w.y = u23; w.z = u45; w.w = u67;         \
        pf[idx] = __builtin_bit_cast(short8, w);                      \
      }
      BUILD_PF(0, SS0, 0)
      BUILD_PF(1, SS0, 8)
      BUILD_PF(2, SS1, 0)
      BUILD_PF(3, SS1, 8)
#undef BUILD_PF
      const u16* Vt = bufv + 4096;
      __builtin_amdgcn_s_setprio(1);
#pragma unroll
      for (int c = 0; c < 4; ++c) {
        short8 vfA = *reinterpret_cast<const short8*>(
            &Vt[ln31 * 64 + ((c * 16 + hi * 8) ^ swz)]);
        short8 vfB = *reinterpret_cast<const short8*>(
            &Vt[(32 + ln31) * 64 + ((c * 16 + hi * 8) ^ swz)]);
        accO0 = mfma32(vfA, pf[c], accO0);
        accO1 = mfma32(vfB, pf[c], accO1);
      }
      __builtin_amdgcn_s_setprio(0);
    };

    const int nt = 2 * (tq + 1);

    __syncthreads();
    stage_k(0, smem[0]);
    {
      short8 v0, v1;
      load_v(0, v0, v1);
      write_v(smem[0], v0, v1);
    }
    stage_k(64, smem[1]);
    {
      short8 v0, v1;
      load_v(64, v0, v1);
      write_v(smem[1], v0, v1);
    }
    __syncthreads();

    floatx16 SA0, SA1, SB0, SB1;
    do_qk(0, SA0, SA1, smem[0]);

    for (int it = 0; it < nt; it += 2) {
      {
        const int kvc = it * 64;
        short8 nv0, nv1;
        const bool do_st = (it + 2) < nt;
        u16* sbuf = smem[(it + 2) % 3];
        if (do_st) {
          stage_k(kvc + 128, sbuf);
          load_v(kvc + 128, nv0, nv1);
        }
        do_qk(kvc + 64, SB0, SB1, smem[(it + 1) % 3]);
        do_smpv(kvc, SA0, SA1, smem[it % 3]);
        if (do_st) write_v(sbuf, nv0, nv1);
        __syncthreads();
      }
      {
        const int kvc = it * 64 + 64;
        short8 nv0, nv1;
        const bool do_st = (it + 3) < nt;
        u16* sbuf = smem[(it + 3) % 3];
        if (do_st) {
          stage_k(kvc + 128, sbuf);
          load_v(kvc + 128, nv0, nv1);
        }
        if (it + 2 < nt) do_qk(kvc + 64, SA0, SA1, smem[(it + 2) % 3]);
        do_smpv(kvc, SB0, SB1, smem[(it + 1) % 3]);
        if (do_st) write_v(sbuf, nv0, nv1);
        __syncthreads();
      }
    }

    u16* ep = &smem[0][0] + wave * 2048;
    float inv = 1.0f / l_run;
#define EPI_W(ACC, dh2)                                               \
    {                                                                 \
      _Pragma("unroll")                                               \
      for (int rp = 0; rp < 8; ++rp) {                                \
        int reg = rp * 2;                                             \
        unsigned pk = cvtpk(ACC[reg] * inv, ACC[reg + 1] * inv);      \
        int d = dh2 * 32 + (reg & 3) + 8 * (reg >> 2) + 4 * hi;       \
        *reinterpret_cast<uint32_t*>(                                 \
            &ep[ln31 * 64 + (d ^ ((ln31 & 7) * 8))]) = pk;            \
      }                                                               \
    }
    EPI_W(accO0, 0)
    EPI_W(accO1, 1)
#undef EPI_W
#pragma unroll
    for (int g = 0; g < 4; ++g) {
      int d0 = hi * 32 + g * 8;
      short8 o8 = *reinterpret_cast<const short8*>(
          &ep[ln31 * 64 + (d0 ^ ((ln31 & 7) * 8))]);
      *reinterpret_cast<short8*>(
          &Ob[(size_t)(b * 2048 + q0w + ln31) * 1024 + h * 64 + d0]) = o8;
    }
  }
}

// ---------------------------------------------------------------- launch
extern "C" void kernel_launch(void* const* d_in, const int* in_sizes, int n_in,
                              void* d_out, int out_size, void* d_ws, size_t ws_size,
                              hipStream_t stream) {
  const float* x    = (const float*)d_in[0];   // [4,2048,1024]
  const float* win  = (const float*)d_in[1];   // [3072,1024]
  const float* wout = (const float*)d_in[2];   // [1024,1024]
  float* out = (float*)d_out;                  // [4,2048,1024] f32

  char* ws = (char*)d_ws;
  u16* xb    = (u16*)(ws + 0);          // 16 MB
  u16* winb  = (u16*)(ws + 16777216);   // 6 MB
  u16* woutb = (u16*)(ws + 23068672);   // 2 MB
  u16* Qb    = (u16*)(ws + 25165824);   // 16 MB  [B,H,S,dh] bf16, pre-scaled 0.125*log2e
  u16* Kb    = (u16*)(ws + 41943040);   // 16 MB
  u16* Vb    = (u16*)(ws + 58720256);   // 16 MB
  u16* Ob    = (u16*)(ws + 75497472);   // 16 MB  attn out [B,S,D] bf16

  cast3_kernel<<<12288, 256, 0, stream>>>(x, win, wout, xb, winb, woutb);

  // QKV projection: [8192,1024] x [3072,1024]^T  (BM=128, BN=256, grid 768 = 3/CU)
  gemm_bt<0><<<dim3(12, 64), 512, 0, stream>>>(xb, winb, 8192, 3072, 1024,
                                               Qb, Kb, Vb, nullptr);
  // attention (paired q-tiles, uniform work, XCD-swizzled K/V locality)
  attn_kernel<<<dim3(8, 64), 256, 0, stream>>>(Qb, Kb, Vb, Ob);
  // output projection: [8192,1024] x [1024,1024]^T -> f32  (grid 256 = 1/CU)
  gemm_bt<1><<<dim3(4, 64), 512, 0, stream>>>(Ob, woutb, 8192, 1024, 1024,
                                              nullptr, nullptr, nullptr, out);
}

// Round 21
// 163.193 us; speedup vs baseline: 1.0503x; 1.0503x over previous
//
#include <hip/hip_runtime.h>
#include <hip/hip_bf16.h>
#include <stdint.h>

typedef unsigned short u16;
typedef __attribute__((ext_vector_type(8))) short short8;
typedef __attribute__((ext_vector_type(4))) float floatx4;
typedef __attribute__((ext_vector_type(16))) float floatx16;
typedef __attribute__((ext_vector_type(4))) unsigned uint4v;
typedef __attribute__((ext_vector_type(2))) unsigned uint2v;

#define DEV static __device__ __forceinline__

DEV u16 f2bf(float f) {
  __hip_bfloat16 h = __float2bfloat16(f);
  return __builtin_bit_cast(u16, h);
}

DEV float fexp2(float x) {
  float r;
  asm("v_exp_f32 %0, %1" : "=v"(r) : "v"(x));
  return r;
}

DEV unsigned cvtpk(float lo, float hi) {  // packs (lo,hi) -> 2x bf16 in one u32
  unsigned r;
  asm("v_cvt_pk_bf16_f32 %0, %1, %2" : "=v"(r) : "v"(lo), "v"(hi));
  return r;
}

// v_permlane32_swap_b32 via the intrinsic (pure function -> no register-alias UB)
DEV void pswap(unsigned& a, unsigned& b) {
  uint2v r = __builtin_amdgcn_permlane32_swap(a, b, false, false);
  a = r[0];
  b = r[1];
}

// x = (lane<32 ? self : partner), y = (lane<32 ? partner : self); symmetric combines valid.
DEV void cross32(float v, float& x, float& y) {
  unsigned a = __builtin_bit_cast(unsigned, v), b = a;
  pswap(a, b);
  x = __builtin_bit_cast(float, a);
  y = __builtin_bit_cast(float, b);
}

DEV floatx4 mfma16(short8 a, short8 b, floatx4 c) {
  return __builtin_amdgcn_mfma_f32_16x16x32_bf16(a, b, c, 0, 0, 0);
}
DEV floatx16 mfma32(short8 a, short8 b, floatx16 c) {
  return __builtin_amdgcn_mfma_f32_32x32x16_bf16(a, b, c, 0, 0, 0);
}

DEV void gload_lds16(const void* g, void* l) {
  __builtin_amdgcn_global_load_lds(
      (void __attribute__((address_space(1)))*)(g),
      (void __attribute__((address_space(3)))*)(l),
      16, 0, 0);
}

// ---------------------------------------------------------------- fused cast f32->bf16
__global__ void cast3_kernel(const float* __restrict__ x, const float* __restrict__ win,
                             const float* __restrict__ wout,
                             u16* __restrict__ xb, u16* __restrict__ winb,
                             u16* __restrict__ woutb) {
  int i = blockIdx.x * 256 + threadIdx.x;
  const float* src;
  u16* dst;
  int off;
  if (i < 2097152) {
    src = x; dst = xb; off = i;
  } else if (i < 2883584) {
    src = win; dst = winb; off = i - 2097152;
  } else {
    src = wout; dst = woutb; off = i - 2883584;
  }
  float4 v = reinterpret_cast<const float4*>(src)[off];
  ushort4 o;
  o.x = f2bf(v.x); o.y = f2bf(v.y); o.z = f2bf(v.z); o.w = f2bf(v.w);
  reinterpret_cast<ushort4*>(dst)[off] = o;
}

// ---------------------------------------------------------------- GEMM  C[M,N] = A[M,K] * W[N,K]^T
// ROUND-11 VERSION (validated optimum): phase-split (T3+T4), BM=128 BN=256 BK=64,
// 3 LDS buffers, prefetch distance 2, vmcnt(6) counted, 2 phases per K-tile.
// (r12: +1 barrier/tile = +2us; r20: -1 barrier/tile = +8us -> 2/tile is optimal.)
template <int MODE>
__global__ __launch_bounds__(512, 2)
void gemm_bt(const u16* __restrict__ A, const u16* __restrict__ W,
             int M, int N, int K,
             u16* __restrict__ Qb, u16* __restrict__ Kb, u16* __restrict__ Vb,
             float* __restrict__ C) {
  __shared__ u16 As[3][128 * 64];   // 48 KB
  __shared__ u16 Bs[3][256 * 64];   // 96 KB
  const int tid = threadIdx.x;
  const int wave = tid >> 6, lane = tid & 63;
  const int lr = lane & 15, lg = lane >> 4;
  const int m0 = blockIdx.y * 128, n0 = blockIdx.x * 256;
  const int mq0 = (wave >> 2) * 64, nq0 = (wave & 3) * 64;

  floatx4 acc[4][4];
#pragma unroll
  for (int i = 0; i < 4; ++i)
#pragma unroll
    for (int j = 0; j < 4; ++j) acc[i][j] = (floatx4)0.f;

  const int NT = K >> 6;  // K-tiles of 64

  auto stage_a = [&](int t, int bi) {
#pragma unroll
    for (int i = 0; i < 2; ++i) {
      int s = i * 512 + tid;
      int row = s >> 3;
      int col = ((s & 7) ^ (row & 7)) * 8;
      gload_lds16(&A[(size_t)(m0 + row) * K + t * 64 + col], &As[bi][(size_t)s * 8]);
    }
  };
  auto stage_b = [&](int t, int bi, int i0, int i1) {
#pragma unroll 4
    for (int i = i0; i < i1; ++i) {
      int s = i * 512 + tid;
      int row = s >> 3;
      int col = ((s & 7) ^ (row & 7)) * 8;
      gload_lds16(&W[(size_t)(n0 + row) * K + t * 64 + col], &Bs[bi][(size_t)s * 8]);
    }
  };

  // prologue: tiles 0,1 into bufs 0,1 (12 loads outstanding)
  stage_a(0, 0);
  stage_b(0, 0, 0, 4);
  stage_a(1, 1);
  stage_b(1, 1, 0, 4);

  int bi = 0;
  for (int t = 0; t < NT; ++t) {
    // ---- tile top: own tile-t loads landed (t+1's 6 in flight), all waves sync
    if (t < NT - 1) {
      asm volatile("s_waitcnt vmcnt(6)" ::: "memory");
    } else {
      asm volatile("s_waitcnt vmcnt(0)" ::: "memory");
    }
    __builtin_amdgcn_sched_barrier(0);
    __builtin_amdgcn_s_barrier();
    __builtin_amdgcn_sched_barrier(0);

    int b2 = bi + 2; if (b2 >= 3) b2 -= 3;
    const bool do_st = (t + 2 < NT);

    // ---- phase 0: ds_read af(8)+bf01(4); stage A(2)+B0(1); MFMA j={0,1}
    short8 af[4][2], bf01[2][2];
#pragma unroll
    for (int i = 0; i < 4; ++i) {
      int row = mq0 + i * 16 + lr;
#pragma unroll
      for (int kh = 0; kh < 2; ++kh)
        af[i][kh] = *reinterpret_cast<const short8*>(
            &As[bi][row * 64 + (((kh * 4 + lg) ^ (row & 7)) * 8)]);
    }
#pragma unroll
    for (int j = 0; j < 2; ++j) {
      int row = nq0 + j * 16 + lr;
#pragma unroll
      for (int kh = 0; kh < 2; ++kh)
        bf01[j][kh] = *reinterpret_cast<const short8*>(
            &Bs[bi][row * 64 + (((kh * 4 + lg) ^ (row & 7)) * 8)]);
    }
    if (do_st) {
      stage_a(t + 2, b2);
      stage_b(t + 2, b2, 0, 1);
    }
    __builtin_amdgcn_sched_barrier(0);
    __builtin_amdgcn_s_setprio(1);
#pragma unroll
    for (int kh = 0; kh < 2; ++kh)
#pragma unroll
      for (int i = 0; i < 4; ++i)
#pragma unroll
        for (int j = 0; j < 2; ++j)
          acc[i][j] = mfma16(af[i][kh], bf01[j][kh], acc[i][j]);
    __builtin_amdgcn_s_setprio(0);
    __builtin_amdgcn_sched_barrier(0);
    __builtin_amdgcn_s_barrier();

    // ---- phase 1: ds_read bf23(4); stage B1..3; MFMA j={2,3}
    short8 bf23[2][2];
#pragma unroll
    for (int j = 0; j < 2; ++j) {
      int row = nq0 + (j + 2) * 16 + lr;
#pragma unroll
      for (int kh = 0; kh < 2; ++kh)
        bf23[j][kh] = *reinterpret_cast<const short8*>(
            &Bs[bi][row * 64 + (((kh * 4 + lg) ^ (row & 7)) * 8)]);
    }
    if (do_st) stage_b(t + 2, b2, 1, 4);
    __builtin_amdgcn_sched_barrier(0);
    __builtin_amdgcn_s_setprio(1);
#pragma unroll
    for (int kh = 0; kh < 2; ++kh)
#pragma unroll
      for (int i = 0; i < 4; ++i)
#pragma unroll
        for (int j = 0; j < 2; ++j)
          acc[i][j + 2] = mfma16(af[i][kh], bf23[j][kh], acc[i][j + 2]);
    __builtin_amdgcn_s_setprio(0);
    __builtin_amdgcn_sched_barrier(0);

    if (++bi == 3) bi = 0;
  }

  if (MODE == 0) {
#pragma unroll
    for (int j = 0; j < 4; ++j) {
      int n = n0 + nq0 + j * 16 + lr;
      int which = n >> 10;
      int d = n & 1023;
      int h = d >> 6, dh = d & 63;
      u16* dst = (which == 0) ? Qb : ((which == 1) ? Kb : Vb);
      float scale = (which == 0) ? 0.18033688f : 1.0f;  // 0.125 * log2(e)
#pragma unroll
      for (int i = 0; i < 4; ++i) {
#pragma unroll
        for (int r = 0; r < 4; ++r) {
          int m = m0 + mq0 + i * 16 + lg * 4 + r;
          int b = m >> 11, s = m & 2047;
          dst[((size_t)(b * 16 + h) * 2048 + s) * 64 + dh] = f2bf(acc[i][j][r] * scale);
        }
      }
    }
  } else {
#pragma unroll
    for (int i = 0; i < 4; ++i)
#pragma unroll
      for (int j = 0; j < 4; ++j)
#pragma unroll
        for (int r = 0; r < 4; ++r) {
          int m = m0 + mq0 + i * 16 + lg * 4 + r;
          int n = n0 + nq0 + j * 16 + lr;
          C[(size_t)m * N + n] = acc[i][j][r];
        }
  }
}

// ---------------------------------------------------------------- flash attention (causal)
// ROUND-16/19 VERSION (measured best, attn 75.2 us, total 163.60): round-11
// swapped-operand structure + bijective XCD swizzle (K/V L2-resident).
__global__ __launch_bounds__(256, 2)
void attn_kernel(const u16* __restrict__ Qb, const u16* __restrict__ Kb,
                 const u16* __restrict__ Vb, u16* __restrict__ Ob) {
  // bijective remap (lid <-> (xcd, k)): bh = xcd*8 + (k&7), bx = k>>3
  const int lid = (int)blockIdx.x + 8 * (int)blockIdx.y;
  const int xcd = lid & 7;
  const int kk = lid >> 3;          // 0..63
  const int bh = xcd * 8 + (kk & 7);
  const int bx = kk >> 3;           // 0..7, replaces blockIdx.x
  const u16* Qh = Qb + (size_t)bh * 2048 * 64;
  const u16* Kh = Kb + (size_t)bh * 2048 * 64;
  const u16* Vh = Vb + (size_t)bh * 2048 * 64;

  __shared__ u16 smem[3][8192];

  const int tid = threadIdx.x, wave = tid >> 6, lane = tid & 63;
  const int ln31 = lane & 31, hi = lane >> 5;
  const int swz = (lane & 7) * 8;
  const int b = bh >> 4, h = bh & 15;

  const int vp = tid & 31, vc8 = tid >> 5;

  auto stage_k = [&](int kvbase, u16* buf) {
#pragma unroll
    for (int i = 0; i < 2; ++i) {
      int s = i * 256 + tid;
      int row = s >> 3;
      int col = ((s & 7) ^ (row & 7)) * 8;
      gload_lds16(&Kh[(size_t)(kvbase + row) * 64 + col], &buf[(size_t)s * 8]);
    }
  };
  auto load_v = [&](int kvbase, short8& v0, short8& v1) {
    v0 = *reinterpret_cast<const short8*>(&Vh[(size_t)(kvbase + 2 * vp) * 64 + vc8 * 8]);
    v1 = *reinterpret_cast<const short8*>(&Vh[(size_t)(kvbase + 2 * vp + 1) * 64 + vc8 * 8]);
  };
  auto write_v = [&](u16* buf, short8 v0, short8 v1) {
#pragma unroll
    for (int j = 0; j < 8; ++j) {
      int d = vc8 * 8 + j;
      uint32_t pk = (uint32_t)(u16)v0[j] | ((uint32_t)(u16)v1[j] << 16);
      *reinterpret_cast<uint32_t*>(&buf[4096 + d * 64 + ((2 * vp) ^ ((d & 7) * 8))]) = pk;
    }
  };

  for (int ph = 0; ph < 2; ++ph) {
    const int tq = ph ? (15 - bx) : bx;
    const int q0w = tq * 128 + wave * 32;
    const int qrow = q0w + ln31;

    short8 qf[4];
#pragma unroll
    for (int c = 0; c < 4; ++c)
      qf[c] = *reinterpret_cast<const short8*>(
          &Qh[(size_t)qrow * 64 + c * 16 + hi * 8]);

    floatx16 accO0 = (floatx16)0.f, accO1 = (floatx16)0.f;
    float m_run = -1e30f, l_run = 0.f;

    auto do_qk = [&](int kvq, floatx16& SQ0, floatx16& SQ1, const u16* Ksq) {
      if (kvq > q0w + 31) return;
      SQ0 = (floatx16)0.f;
      SQ1 = (floatx16)0.f;
      __builtin_amdgcn_s_setprio(1);
#pragma unroll
      for (int c = 0; c < 4; ++c) {
        short8 kfA = *reinterpret_cast<const short8*>(
            &Ksq[ln31 * 64 + ((c * 16 + hi * 8) ^ swz)]);
        short8 kfB = *reinterpret_cast<const short8*>(
            &Ksq[(32 + ln31) * 64 + ((c * 16 + hi * 8) ^ swz)]);
        SQ0 = mfma32(kfA, qf[c], SQ0);
        SQ1 = mfma32(kfB, qf[c], SQ1);
      }
      __builtin_amdgcn_s_setprio(0);
    };

    auto do_smpv = [&](int kv0_, floatx16& SS0, floatx16& SS1, const u16* bufv) {
      if (kv0_ > q0w + 31) return;
      if (kv0_ + 63 > q0w) {
#pragma unroll
        for (int reg = 0; reg < 16; ++reg) {
          int kvA = kv0_ + (reg & 3) + 8 * (reg >> 2) + 4 * hi;
          if (kvA > qrow) SS0[reg] = -1e30f;
          if (kvA + 32 > qrow) SS1[reg] = -1e30f;
        }
      }
      float m8[8];
#pragma unroll
      for (int i = 0; i < 8; ++i)
        m8[i] = fmaxf(fmaxf(SS0[i], SS0[i + 8]), fmaxf(SS1[i], SS1[i + 8]));
      float mx = fmaxf(fmaxf(fmaxf(m8[0], m8[1]), fmaxf(m8[2], m8[3])),
                       fmaxf(fmaxf(m8[4], m8[5]), fmaxf(m8[6], m8[7])));
      {
        float xa, xb;
        cross32(mx, xa, xb);
        mx = fmaxf(xa, xb);
      }
      bool small_ = (mx <= m_run + 8.f);
      if (!__all(small_)) {
        float mn = fmaxf(m_run, mx);
        float fac = fexp2(m_run - mn);
        m_run = mn;
        l_run *= fac;
        accO0 *= fac;
        accO1 *= fac;
      }
#pragma unroll
      for (int i = 0; i < 16; ++i) SS0[i] = fexp2(SS0[i] - m_run);
#pragma unroll
      for (int i = 0; i < 16; ++i) SS1[i] = fexp2(SS1[i] - m_run);
      float a8[8];
#pragma unroll
      for (int i = 0; i < 8; ++i)
        a8[i] = (SS0[i] + SS0[i + 8]) + (SS1[i] + SS1[i + 8]);
      float rs = ((a8[0] + a8[1]) + (a8[2] + a8[3])) + ((a8[4] + a8[5]) + (a8[6] + a8[7]));
      {
        float xa, xb;
        cross32(rs, xa, xb);
        rs = xa + xb;
      }
      l_run += rs;
      short8 pf[4];
#define BUILD_PF(idx, S, base)                                        \
      {                                                               \
        unsigned u01 = cvtpk(S[base + 0], S[base + 1]);               \
        unsigned u23 = cvtpk(S[base + 2], S[base + 3]);               \
        unsigned u45 = cvtpk(S[base + 4], S[base + 5]);               \
        unsigned u67 = cvtpk(S[base + 6], S[base + 7]);               \
        pswap(u01, u45);                                              \
        pswap(u23, u67);                                              \
        uint4v w; w.x = u01; w.y = u23; w.z = u45; w.w = u67;         \
        pf[idx] = __builtin_bit_cast(short8, w);                      \
      }
      BUILD_PF(0, SS0, 0)
      BUILD_PF(1, SS0, 8)
      BUILD_PF(2, SS1, 0)
      BUILD_PF(3, SS1, 8)
#undef BUILD_PF
      const u16* Vt = bufv + 4096;
      __builtin_amdgcn_s_setprio(1);
#pragma unroll
      for (int c = 0; c < 4; ++c) {
        short8 vfA = *reinterpret_cast<const short8*>(
            &Vt[ln31 * 64 + ((c * 16 + hi * 8) ^ swz)]);
        short8 vfB = *reinterpret_cast<const short8*>(
            &Vt[(32 + ln31) * 64 + ((c * 16 + hi * 8) ^ swz)]);
        accO0 = mfma32(vfA, pf[c], accO0);
        accO1 = mfma32(vfB, pf[c], accO1);
      }
      __builtin_amdgcn_s_setprio(0);
    };

    const int nt = 2 * (tq + 1);

    __syncthreads();
    stage_k(0, smem[0]);
    {
      short8 v0, v1;
      load_v(0, v0, v1);
      write_v(smem[0], v0, v1);
    }
    stage_k(64, smem[1]);
    {
      short8 v0, v1;
      load_v(64, v0, v1);
      write_v(smem[1], v0, v1);
    }
    __syncthreads();

    floatx16 SA0, SA1, SB0, SB1;
    do_qk(0, SA0, SA1, smem[0]);

    for (int it = 0; it < nt; it += 2) {
      {
        const int kvc = it * 64;
        short8 nv0, nv1;
        const bool do_st = (it + 2) < nt;
        u16* sbuf = smem[(it + 2) % 3];
        if (do_st) {
          stage_k(kvc + 128, sbuf);
          load_v(kvc + 128, nv0, nv1);
        }
        do_qk(kvc + 64, SB0, SB1, smem[(it + 1) % 3]);
        do_smpv(kvc, SA0, SA1, smem[it % 3]);
        if (do_st) write_v(sbuf, nv0, nv1);
        __syncthreads();
      }
      {
        const int kvc = it * 64 + 64;
        short8 nv0, nv1;
        const bool do_st = (it + 3) < nt;
        u16* sbuf = smem[(it + 3) % 3];
        if (do_st) {
          stage_k(kvc + 128, sbuf);
          load_v(kvc + 128, nv0, nv1);
        }
        if (it + 2 < nt) do_qk(kvc + 64, SA0, SA1, smem[(it + 2) % 3]);
        do_smpv(kvc, SB0, SB1, smem[(it + 1) % 3]);
        if (do_st) write_v(sbuf, nv0, nv1);
        __syncthreads();
      }
    }

    u16* ep = &smem[0][0] + wave * 2048;
    float inv = 1.0f / l_run;
#define EPI_W(ACC, dh2)                                               \
    {                                                                 \
      _Pragma("unroll")                                               \
      for (int rp = 0; rp < 8; ++rp) {                                \
        int reg = rp * 2;                                             \
        unsigned pk = cvtpk(ACC[reg] * inv, ACC[reg + 1] * inv);      \
        int d = dh2 * 32 + (reg & 3) + 8 * (reg >> 2) + 4 * hi;       \
        *reinterpret_cast<uint32_t*>(                                 \
            &ep[ln31 * 64 + (d ^ ((ln31 & 7) * 8))]) = pk;            \
      }                                                               \
    }
    EPI_W(accO0, 0)
    EPI_W(accO1, 1)
#undef EPI_W
#pragma unroll
    for (int g = 0; g < 4; ++g) {
      int d0 = hi * 32 + g * 8;
      short8 o8 = *reinterpret_cast<const short8*>(
          &ep[ln31 * 64 + (d0 ^ ((ln31 & 7) * 8))]);
      *reinterpret_cast<short8*>(
          &Ob[(size_t)(b * 2048 + q0w + ln31) * 1024 + h * 64 + d0]) = o8;
    }
  }
}

// ---------------------------------------------------------------- launch
extern "C" void kernel_launch(void* const* d_in, const int* in_sizes, int n_in,
                              void* d_out, int out_size, void* d_ws, size_t ws_size,
                              hipStream_t stream) {
  const float* x    = (const float*)d_in[0];   // [4,2048,1024]
  const float* win  = (const float*)d_in[1];   // [3072,1024]
  const float* wout = (const float*)d_in[2];   // [1024,1024]
  float* out = (float*)d_out;                  // [4,2048,1024] f32

  char* ws = (char*)d_ws;
  u16* xb    = (u16*)(ws + 0);          // 16 MB
  u16* winb  = (u16*)(ws + 16777216);   // 6 MB
  u16* woutb = (u16*)(ws + 23068672);   // 2 MB
  u16* Qb    = (u16*)(ws + 25165824);   // 16 MB  [B,H,S,dh] bf16, pre-scaled 0.125*log2e
  u16* Kb    = (u16*)(ws + 41943040);   // 16 MB
  u16* Vb    = (u16*)(ws + 58720256);   // 16 MB
  u16* Ob    = (u16*)(ws + 75497472);   // 16 MB  attn out [B,S,D] bf16

  cast3_kernel<<<12288, 256, 0, stream>>>(x, win, wout, xb, winb, woutb);

  // QKV projection: [8192,1024] x [3072,1024]^T  (BM=128, BN=256, grid 768 = 3/CU)
  gemm_bt<0><<<dim3(12, 64), 512, 0, stream>>>(xb, winb, 8192, 3072, 1024,
                                               Qb, Kb, Vb, nullptr);
  // attention (paired q-tiles, uniform work, XCD-swizzled K/V locality)
  attn_kernel<<<dim3(8, 64), 256, 0, stream>>>(Qb, Kb, Vb, Ob);
  // output projection: [8192,1024] x [1024,1024]^T -> f32  (grid 256 = 1/CU)
  gemm_bt<1><<<dim3(4, 64), 512, 0, stream>>>(Ob, woutb, 8192, 1024, 1024,
                                              nullptr, nullptr, nullptr, out);
}